// Round 7
// baseline (53.016 us; speedup 1.0000x reference)
//
#include <hip/hip_runtime.h>
#include <math.h>

#define BB 64
#define PP 16
#define FIN 672
#define HH 2048
#define AA 32
#define MM (BB*PP)     // 1024
#define EPSBN 1e-5f
#define NKB 21         // FIN/32

typedef _Float16 f16;
typedef __attribute__((ext_vector_type(8))) _Float16 half8;
typedef __attribute__((ext_vector_type(4))) float floatx4;

// S(h) for the 16-step LIF with constant drive h: spike period m = ceil(-log2(1-1/h)),
// S = sum over spikes q*m<=16 of KC[q*m-1]; exact dyadic values precomputed.
__device__ const float LIF_LUT[18] = {
    0.0f,
    0.93750095367431640625f,   // m=1  (0.9375 + 2^-20)
    0.4583339691162109375f,    // m=2
    0.294643402099609375f,     // m=3
    0.21666717529296875f,      // m=4
    0.1713714599609375f,       // m=5
    0.123016357421875f,        // m=6
    0.11712646484375f,         // m=7
    0.0936279296875f,          // m=8
    0.062255859375f,           // m=9
    0.06201171875f,            // m=10
    0.0615234375f,             // m=11
    0.060546875f,              // m=12
    0.05859375f,               // m=13
    0.0546875f,                // m=14
    0.046875f,                 // m=15
    0.03125f,                  // m=16
    0.0f                       // m>=17: no spike
};

// ---------------------------------------------------------------------------
// Fused prep:
//  blocks [0,448):    A planes  (BN0 + f16 hi/lo, MFMA-A frag order)
//  blocks [448,1120): W1 planes (f16 hi/lo, MFMA-B frag order)
//  blocks [1120,1184): w2 frag planes (f16 hi/lo, MFMA-B frag order, N=32)
// Frag layout: plane[(tile*NKB + kb)*64 + lane][8 f16]  (1 KB per frag chunk)
// ---------------------------------------------------------------------------
__global__ __launch_bounds__(256) void k_prep(
    const float* __restrict__ x, const float* __restrict__ w1,
    const float* __restrict__ w2,
    const float* __restrict__ g0, const float* __restrict__ b0,
    const float* __restrict__ m0, const float* __restrict__ v0,
    f16* __restrict__ Ah, f16* __restrict__ Al,
    f16* __restrict__ Wh, f16* __restrict__ Wl,
    f16* __restrict__ W2h, f16* __restrict__ W2l)
{
    __shared__ float sbuf[32 * 65];
    const int tid = threadIdx.x;
    const int b   = blockIdx.x;

    if (b < 448) {
        // ---- A role: mb = b/7 (16-row group), kc = b%7 (96-k chunk) ----
        const int mb = b / 7;
        const int kc = b % 7;
        #pragma unroll
        for (int i = 0; i < 2; ++i) {
            const int f4 = tid + 256 * i;
            if (f4 < 384) {
                const int row = f4 / 24;
                const int c4  = (f4 % 24) * 4;
                float4 v = *(const float4*)(x + (size_t)(mb * 16 + row) * FIN + kc * 96 + c4);
                sbuf[row * 97 + c4 + 0] = v.x; sbuf[row * 97 + c4 + 1] = v.y;
                sbuf[row * 97 + c4 + 2] = v.z; sbuf[row * 97 + c4 + 3] = v.w;
            }
        }
        __syncthreads();
        if (tid < 192) {
            const int fi   = tid >> 6;          // 0..2 kb-in-chunk
            const int lane = tid & 63;
            const int row  = lane & 15;
            const int koff = fi * 32 + ((lane >> 4) << 3);
            const float a0  = g0[row] / sqrtf(v0[row] + EPSBN);
            const float be0 = b0[row] - m0[row] * a0;
            half8 hi, lo;
            #pragma unroll
            for (int j = 0; j < 8; ++j) {
                const float xn = fmaf(a0, sbuf[row * 97 + koff + j], be0);
                const f16 h = (f16)xn;
                hi[j] = h;
                lo[j] = (f16)(xn - (float)h);
            }
            const int kb = kc * 3 + fi;
            const size_t idx = ((size_t)(mb * NKB + kb) * 64 + lane);
            *(half8*)(Ah + idx * 8) = hi;
            *(half8*)(Al + idx * 8) = lo;
        }
    } else if (b < 1120) {
        // ---- W1 role: ng = 64-col group, kb = 32-k block ----
        const int bw = b - 448;
        const int ng = bw & 31;
        const int kb = bw >> 5;     // 0..20
        #pragma unroll
        for (int i = 0; i < 2; ++i) {
            const int f4  = tid + 256 * i;        // 0..511
            const int row = f4 >> 4;
            const int c4  = (f4 & 15) * 4;
            float4 v = *(const float4*)(w1 + (size_t)(kb * 32 + row) * HH + ng * 64 + c4);
            sbuf[row * 65 + c4 + 0] = v.x; sbuf[row * 65 + c4 + 1] = v.y;
            sbuf[row * 65 + c4 + 2] = v.z; sbuf[row * 65 + c4 + 3] = v.w;
        }
        __syncthreads();
        const int fi   = tid >> 6;     // 0..3
        const int lane = tid & 63;
        const int col  = fi * 16 + (lane & 15);
        const int kr   = (lane >> 4) << 3;
        half8 hi, lo;
        #pragma unroll
        for (int j = 0; j < 8; ++j) {
            const float wv = sbuf[(kr + j) * 65 + col];
            const f16 h = (f16)wv;
            hi[j] = h;
            lo[j] = (f16)(wv - (float)h);
        }
        const int nb = ng * 4 + fi;
        const size_t idx = ((size_t)(nb * NKB + kb) * 64 + lane);
        *(half8*)(Wh + idx * 8) = hi;
        *(half8*)(Wl + idx * 8) = lo;
    } else {
        // ---- w2 role: kb = 32-k block (64 blocks), N = 32 ----
        const int kb  = b - 1120;   // 0..63
        const int row = tid >> 3;
        const int c4  = (tid & 7) << 2;
        if (c4 < AA) {
            float4 v = *(const float4*)(w2 + (size_t)(kb * 32 + row) * AA + c4);
            sbuf[row * 33 + c4 + 0] = v.x; sbuf[row * 33 + c4 + 1] = v.y;
            sbuf[row * 33 + c4 + 2] = v.z; sbuf[row * 33 + c4 + 3] = v.w;
        }
        __syncthreads();
        if (tid < 128) {
            const int nb   = tid >> 6;     // 0..1
            const int lane = tid & 63;
            const int col  = nb * 16 + (lane & 15);
            const int kr   = (lane >> 4) << 3;
            half8 hi, lo;
            #pragma unroll
            for (int j = 0; j < 8; ++j) {
                const float wv = sbuf[(kr + j) * 33 + col];
                const f16 h = (f16)wv;
                hi[j] = h;
                lo[j] = (f16)(wv - (float)h);
            }
            const size_t idx = ((size_t)(kb * 2 + nb) * 64 + lane);
            *(half8*)(W2h + idx * 8) = hi;
            *(half8*)(W2l + idx * 8) = lo;
        }
    }
}

// ---------------------------------------------------------------------------
// GEMM1: LDS-staged MFMA f16-split (hh+hl+lh), fused bias1/BN1/LIF -> S f16.
// Block 64x128, 4 waves (wave tile 32x64), grid 256 = 1 block/CU.
// Double-buffered LDS, global_load_lds width=16 from frag planes (layouts
// match 1:1 - each 1KB frag chunk stages with ONE gload_lds instruction).
// XCD swizzle: blockIdx&7 -> 256-col W stripe; A(2.75M)+stripe(0.69M) < 4M L2.
// ---------------------------------------------------------------------------
#define GLOAD16(g, l) __builtin_amdgcn_global_load_lds(                        \
    (const __attribute__((address_space(1))) void*)(g),                       \
    (__attribute__((address_space(3))) void*)(l), 16, 0, 0)

__global__ __launch_bounds__(256) void k_gemm1_lds(
    const f16* __restrict__ Ah, const f16* __restrict__ Al,
    const f16* __restrict__ Wh, const f16* __restrict__ Wl,
    const float* __restrict__ bias1,
    const float* __restrict__ g1, const float* __restrict__ b1,
    const float* __restrict__ m1, const float* __restrict__ v1,
    f16* __restrict__ S)
{
    __shared__ __align__(16) char smem[49152];   // 2 x 24 chunks x 1KB
    __shared__ float lut[18];

    const int tid  = threadIdx.x;
    const int lane = tid & 63;
    const int w    = tid >> 6;          // 0..3
    const int wm   = w >> 1, wn = w & 1;
    if (tid < 18) lut[tid] = LIF_LUT[tid];

    const int b   = blockIdx.x;         // 0..255
    const int xcd = b & 7;
    const int idx = b >> 3;             // 0..31
    const int bn  = xcd * 2 + (idx & 1);    // 0..15 : 128-col tile
    const int bm  = idx >> 1;               // 0..15 : 64-row tile

    // my 6 staging chunks: c = w*6+q.  chunk map:
    // 0..3 A-hi(mb loc), 4..7 A-lo, 8..15 W-hi(nb loc), 16..23 W-lo
    const char* srcs[6];
    int ldsoff[6];
    #pragma unroll
    for (int q = 0; q < 6; ++q) {
        const int c = w * 6 + q;
        const char* plane; int tile;
        if (c < 4)       { plane = (const char*)Ah; tile = bm * 4 + c; }
        else if (c < 8)  { plane = (const char*)Al; tile = bm * 4 + (c - 4); }
        else if (c < 16) { plane = (const char*)Wh; tile = bn * 8 + (c - 8); }
        else             { plane = (const char*)Wl; tile = bn * 8 + (c - 16); }
        srcs[q]   = plane + (size_t)tile * NKB * 1024 + lane * 16;
        ldsoff[q] = c * 1024;
    }

#define STAGE(kb, bufsel) do {                                                \
    _Pragma("unroll") for (int q_ = 0; q_ < 6; ++q_)                          \
        GLOAD16(srcs[q_] + (kb) * 1024, smem + (bufsel) * 24576 + ldsoff[q_]);\
} while (0)

    floatx4 acc[2][4];
    #pragma unroll
    for (int m = 0; m < 2; ++m)
        #pragma unroll
        for (int n = 0; n < 4; ++n) acc[m][n] = (floatx4){0.f,0.f,0.f,0.f};

    STAGE(0, 0);
    __syncthreads();

    int cur = 0;
    for (int kb = 0; kb < NKB; ++kb) {
        if (kb + 1 < NKB) STAGE(kb + 1, cur ^ 1);

        const char* bufp = smem + cur * 24576 + lane * 16;
        half8 ah[2], al[2], wh[4], wl[4];
        #pragma unroll
        for (int i = 0; i < 2; ++i) {
            ah[i] = *(const half8*)(bufp + (wm * 2 + i) * 1024);
            al[i] = *(const half8*)(bufp + (4 + wm * 2 + i) * 1024);
        }
        #pragma unroll
        for (int n = 0; n < 4; ++n) {
            wh[n] = *(const half8*)(bufp + (8 + wn * 4 + n) * 1024);
            wl[n] = *(const half8*)(bufp + (16 + wn * 4 + n) * 1024);
        }

        #pragma unroll
        for (int m = 0; m < 2; ++m)
            #pragma unroll
            for (int n = 0; n < 4; ++n)
                acc[m][n] = __builtin_amdgcn_mfma_f32_16x16x32_f16(
                    ah[m], wh[n], acc[m][n], 0, 0, 0);
        #pragma unroll
        for (int m = 0; m < 2; ++m)
            #pragma unroll
            for (int n = 0; n < 4; ++n)
                acc[m][n] = __builtin_amdgcn_mfma_f32_16x16x32_f16(
                    ah[m], wl[n], acc[m][n], 0, 0, 0);
        #pragma unroll
        for (int m = 0; m < 2; ++m)
            #pragma unroll
            for (int n = 0; n < 4; ++n)
                acc[m][n] = __builtin_amdgcn_mfma_f32_16x16x32_f16(
                    al[m], wh[n], acc[m][n], 0, 0, 0);

        __syncthreads();
        cur ^= 1;
    }
#undef STAGE

    // ---- fused bias1 / BN1 / LIF-LUT epilogue -> S f16 ----
    const float H16 = (float)(65536.0 / 65535.0);
    const int   r4  = (lane >> 4) << 2;
    float a1c[4], be1c[4];
    #pragma unroll
    for (int j = 0; j < 4; ++j) {
        const int p = r4 + j;
        a1c[j]  = g1[p] / sqrtf(v1[p] + EPSBN);
        be1c[j] = b1[p] - m1[p] * a1c[j];
    }

    #pragma unroll
    for (int n = 0; n < 4; ++n) {
        const int col = bn * 128 + wn * 64 + n * 16 + (lane & 15);
        const float bs = bias1[col];
        #pragma unroll
        for (int m = 0; m < 2; ++m) {
            const int rowb = bm * 64 + wm * 32 + m * 16 + r4;
            #pragma unroll
            for (int j = 0; j < 4; ++j) {
                const float h = fmaf(a1c[j], acc[m][n][j] + bs, be1c[j]);
                float s = 0.f;
                if (h >= H16) {
                    const float rr = 1.f - __builtin_amdgcn_rcpf(h);
                    int mi = (int)ceilf(-__log2f(rr));
                    mi = mi < 1 ? 1 : (mi > 17 ? 17 : mi);
                    s = lut[mi];
                }
                S[(size_t)(rowb + j) * HH + col] = (f16)s;
            }
        }
    }
}

// ---------------------------------------------------------------------------
// GEMM2 via MFMA (S f16 x w2 hi/lo f16 = exact w2) + fused BN2/bias2/tanh.
// 64 blocks x 4 waves; block = one 16-row m-tile; waves split K (16 kb each);
// LDS reduce; epilogue writes d_out directly.
// ---------------------------------------------------------------------------
__global__ __launch_bounds__(256) void k_gemm2(
    const f16* __restrict__ S,
    const f16* __restrict__ W2h, const f16* __restrict__ W2l,
    const float* __restrict__ bias2,
    const float* __restrict__ g2, const float* __restrict__ b2,
    const float* __restrict__ m2, const float* __restrict__ v2,
    float* __restrict__ out)
{
    __shared__ float sred[4][2][64][4];
    const int tid  = threadIdx.x;
    const int lane = tid & 63;
    const int w    = tid >> 6;
    const int mt   = blockIdx.x;    // 0..63

    const f16* Sbase = S + (size_t)(mt * 16 + (lane & 15)) * HH + ((lane >> 4) << 3);

    floatx4 acc[2];
    acc[0] = (floatx4){0.f,0.f,0.f,0.f};
    acc[1] = (floatx4){0.f,0.f,0.f,0.f};

    #pragma unroll 4
    for (int t = 0; t < 16; ++t) {
        const int kb = w * 16 + t;
        half8 sf = *(const half8*)(Sbase + kb * 32);
        #pragma unroll
        for (int n = 0; n < 2; ++n) {
            half8 whf = *(const half8*)(W2h + ((size_t)(kb * 2 + n) * 64 + lane) * 8);
            half8 wlf = *(const half8*)(W2l + ((size_t)(kb * 2 + n) * 64 + lane) * 8);
            acc[n] = __builtin_amdgcn_mfma_f32_16x16x32_f16(sf, whf, acc[n], 0, 0, 0);
            acc[n] = __builtin_amdgcn_mfma_f32_16x16x32_f16(sf, wlf, acc[n], 0, 0, 0);
        }
    }

    #pragma unroll
    for (int n = 0; n < 2; ++n)
        #pragma unroll
        for (int j = 0; j < 4; ++j) sred[w][n][lane][j] = acc[n][j];
    __syncthreads();

    if (tid < 64) {
        const int r4 = (lane >> 4) << 2;
        const float Csum = 0.9375f + 0x1p-20f;
        #pragma unroll
        for (int n = 0; n < 2; ++n) {
            #pragma unroll
            for (int j = 0; j < 4; ++j) {
                const float a = sred[0][n][lane][j] + sred[1][n][lane][j]
                              + sred[2][n][lane][j] + sred[3][n][lane][j];
                const int p   = r4 + j;
                const int row = mt * 16 + p;
                const int col = n * 16 + (lane & 15);
                const float a2v = g2[p] / sqrtf(v2[p] + EPSBN);
                const float be2 = b2[p] - m2[p] * a2v;
                const float val = fmaf(a2v, a + Csum * bias2[col], Csum * be2);
                out[row * AA + col] = 2.0f * tanhf(val);
            }
        }
    }
}

// ---------------------------------------------------------------------------
// Fallback path (only if ws too small): fp32 LDS GEMM1 -> f16 S -> gemm2.
// ---------------------------------------------------------------------------
__global__ __launch_bounds__(256) void k_gemm1_fp32(
    const float* __restrict__ x, const float* __restrict__ w1,
    const float* __restrict__ bias1,
    const float* __restrict__ g0, const float* __restrict__ b0,
    const float* __restrict__ m0, const float* __restrict__ v0,
    const float* __restrict__ g1, const float* __restrict__ b1,
    const float* __restrict__ m1, const float* __restrict__ v1,
    f16* __restrict__ S)
{
    __shared__ float As[16][36];
    __shared__ float Bs[16][68];

    const int tid = threadIdx.x;
    const int bx  = blockIdx.x;
    const int by  = blockIdx.y;

    const int ar   = tid & 31;
    const int ak   = (tid >> 5) << 1;
    const int grow = by * 32 + ar;
    const int pA   = grow & 15;
    const float a0  = g0[pA] / sqrtf(v0[pA] + EPSBN);
    const float be0 = b0[pA] - m0[pA] * a0;
    const float* xrow = x + (size_t)grow * FIN;

    const int brk = tid >> 4;
    const int bcc = (tid & 15) << 2;
    const float* wp = w1 + (size_t)brk * HH + bx * 64 + bcc;

    const int tx = tid & 15;
    const int ty = tid >> 4;

    float acc[2][4];
    #pragma unroll
    for (int i = 0; i < 2; ++i)
        #pragma unroll
        for (int j = 0; j < 4; ++j) acc[i][j] = 0.f;

    float2 aPre = *(const float2*)(xrow + ak);
    float4 bPre = *(const float4*)(wp);

    for (int kt = 0; kt < FIN; kt += 16) {
        As[ak + 0][ar] = fmaf(a0, aPre.x, be0);
        As[ak + 1][ar] = fmaf(a0, aPre.y, be0);
        *(float4*)&Bs[brk][bcc] = bPre;
        __syncthreads();
        if (kt + 16 < FIN) {
            aPre = *(const float2*)(xrow + kt + 16 + ak);
            bPre = *(const float4*)(wp + (size_t)(kt + 16) * HH);
        }
        #pragma unroll
        for (int k = 0; k < 16; ++k) {
            float2 a2 = *(const float2*)&As[k][ty << 1];
            float4 b4 = *(const float4*)&Bs[k][tx << 2];
            float aa[2] = {a2.x, a2.y};
            float bb[4] = {b4.x, b4.y, b4.z, b4.w};
            #pragma unroll
            for (int i = 0; i < 2; ++i)
                #pragma unroll
                for (int j = 0; j < 4; ++j)
                    acc[i][j] = fmaf(aa[i], bb[j], acc[i][j]);
        }
        __syncthreads();
    }

    const float KC[16] = {
        (1.0f-0x1p-16f)*0.0625f,(1.0f-0x1p-15f)*0.0625f,(1.0f-0x1p-14f)*0.0625f,(1.0f-0x1p-13f)*0.0625f,
        (1.0f-0x1p-12f)*0.0625f,(1.0f-0x1p-11f)*0.0625f,(1.0f-0x1p-10f)*0.0625f,(1.0f-0x1p-9f)*0.0625f,
        (1.0f-0x1p-8f)*0.0625f,(1.0f-0x1p-7f)*0.0625f,(1.0f-0x1p-6f)*0.0625f,(1.0f-0x1p-5f)*0.0625f,
        (1.0f-0x1p-4f)*0.0625f,(1.0f-0x1p-3f)*0.0625f,(1.0f-0x1p-2f)*0.0625f,(1.0f-0x1p-1f)*0.0625f
    };

    const int col0 = bx * 64 + (tx << 2);
    float4 bias4 = *(const float4*)(bias1 + col0);
    const float bias_arr[4] = {bias4.x, bias4.y, bias4.z, bias4.w};

    #pragma unroll
    for (int i = 0; i < 2; ++i) {
        const int r = by * 32 + (ty << 1) + i;
        const int p = r & 15;
        const float a1  = g1[p] / sqrtf(v1[p] + EPSBN);
        const float be1 = b1[p] - m1[p] * a1;
        #pragma unroll
        for (int j = 0; j < 4; ++j) {
            const float h = fmaf(a1, acc[i][j] + bias_arr[j], be1);
            float v = 0.f, s = 0.f;
            #pragma unroll
            for (int t = 0; t < 16; ++t) {
                v = v + (h - v) * 0.5f;
                if (v >= 1.0f) { s += KC[t]; v = 0.f; }
            }
            S[(size_t)r * HH + col0 + j] = (f16)s;
        }
    }
}

__global__ __launch_bounds__(256) void k_gemm2_part_f16(
    const f16* __restrict__ S, const float* __restrict__ w2,
    float* __restrict__ part2)
{
    __shared__ float w2s[8192];
    const int tid = threadIdx.x;
    const int rg  = blockIdx.x;
    const int kc  = blockIdx.y;

    const float4* src = (const float4*)(w2 + (size_t)kc * 8192);
    #pragma unroll
    for (int i = tid; i < 2048; i += 256) ((float4*)w2s)[i] = src[i];
    __syncthreads();

    const int rw  = tid >> 5;
    const int col = tid & 31;
    const int row = rg * 8 + rw;
    const f16* Sp = S + (size_t)row * HH + kc * 256;

    float acc0 = 0.f, acc1 = 0.f;
    #pragma unroll 4
    for (int j = 0; j < 256; j += 8) {
        half8 s8 = *(const half8*)(Sp + j);
        acc0 = fmaf((float)s8[0], w2s[(j + 0) * 32 + col], acc0);
        acc1 = fmaf((float)s8[1], w2s[(j + 1) * 32 + col], acc1);
        acc0 = fmaf((float)s8[2], w2s[(j + 2) * 32 + col], acc0);
        acc1 = fmaf((float)s8[3], w2s[(j + 3) * 32 + col], acc1);
        acc0 = fmaf((float)s8[4], w2s[(j + 4) * 32 + col], acc0);
        acc1 = fmaf((float)s8[5], w2s[(j + 5) * 32 + col], acc1);
        acc0 = fmaf((float)s8[6], w2s[(j + 6) * 32 + col], acc0);
        acc1 = fmaf((float)s8[7], w2s[(j + 7) * 32 + col], acc1);
    }
    part2[((size_t)kc * MM + row) * AA + col] = acc0 + acc1;
}

__global__ __launch_bounds__(256) void k_finish(
    const float* __restrict__ part2, const float* __restrict__ bias2,
    const float* __restrict__ g2, const float* __restrict__ b2,
    const float* __restrict__ m2, const float* __restrict__ v2,
    float* __restrict__ out)
{
    const int i   = blockIdx.x * 256 + threadIdx.x;
    const int col = i & 31;
    const int row = i >> 5;
    const int p   = row & 15;
    float acc = 0.f;
    #pragma unroll
    for (int s = 0; s < 8; ++s) acc += part2[(size_t)s * MM * AA + i];
    const float a2   = g2[p] / sqrtf(v2[p] + EPSBN);
    const float be2  = b2[p] - m2[p] * a2;
    const float Csum = 0.9375f + 0x1p-20f;
    const float val  = fmaf(a2, acc + Csum * bias2[col], Csum * be2);
    out[i] = 2.0f * tanhf(val);
}

extern "C" void kernel_launch(void* const* d_in, const int* in_sizes, int n_in,
                              void* d_out, int out_size, void* d_ws, size_t ws_size,
                              hipStream_t stream) {
    (void)in_sizes; (void)n_in; (void)out_size;
    const float* x     = (const float*)d_in[0];
    const float* w1    = (const float*)d_in[1];
    const float* bias1 = (const float*)d_in[2];
    const float* w2    = (const float*)d_in[3];
    const float* bias2 = (const float*)d_in[4];
    const float* g0 = (const float*)d_in[5];
    const float* b0 = (const float*)d_in[6];
    const float* m0 = (const float*)d_in[7];
    const float* v0 = (const float*)d_in[8];
    const float* g1 = (const float*)d_in[9];
    const float* b1 = (const float*)d_in[10];
    const float* m1 = (const float*)d_in[11];
    const float* v1 = (const float*)d_in[12];
    const float* g2 = (const float*)d_in[13];
    const float* b2 = (const float*)d_in[14];
    const float* m2 = (const float*)d_in[15];
    const float* v2 = (const float*)d_in[16];
    float* out = (float*)d_out;

    // ws: Ah 1.31M | Al 1.31M | Wh 2.62M | Wl 2.62M | W2h 128K | W2l 128K | S 4M
    const size_t offAl  = 1376256;
    const size_t offWh  = 2752512;
    const size_t offWl  = 5505024;
    const size_t offW2h = 8257536;
    const size_t offW2l = 8388608;
    const size_t offS   = 8519680;
    const size_t needed = offS + 4194304;   // 12713984

    if (ws_size >= needed) {
        f16* Ah  = (f16*)d_ws;
        f16* Al  = (f16*)((char*)d_ws + offAl);
        f16* Wh  = (f16*)((char*)d_ws + offWh);
        f16* Wl  = (f16*)((char*)d_ws + offWl);
        f16* W2h = (f16*)((char*)d_ws + offW2h);
        f16* W2l = (f16*)((char*)d_ws + offW2l);
        f16* S   = (f16*)((char*)d_ws + offS);

        k_prep<<<1184, 256, 0, stream>>>(x, w1, w2, g0, b0, m0, v0,
                                         Ah, Al, Wh, Wl, W2h, W2l);
        k_gemm1_lds<<<256, 256, 0, stream>>>(Ah, Al, Wh, Wl, bias1,
                                             g1, b1, m1, v1, S);
        k_gemm2<<<64, 256, 0, stream>>>(S, W2h, W2l, bias2,
                                        g2, b2, m2, v2, out);
    } else {
        f16* S       = (f16*)d_ws;
        float* part2 = (float*)((char*)d_ws + (size_t)MM * HH * sizeof(f16));
        k_gemm1_fp32<<<dim3(32, 32), 256, 0, stream>>>(x, w1, bias1,
                                                       g0, b0, m0, v0,
                                                       g1, b1, m1, v1, S);
        k_gemm2_part_f16<<<dim3(128, 8), 256, 0, stream>>>(S, w2, part2);
        k_finish<<<dim3(128), 256, 0, stream>>>(part2, bias2, g2, b2, m2, v2, out);
    }
}

// Round 8
// 38.376 us; speedup vs baseline: 1.3815x; 1.3815x over previous
//
#include <hip/hip_runtime.h>
#include <math.h>

#define BB 64
#define PP 16
#define FIN 672
#define HH 2048
#define AA 32
#define MM (BB*PP)     // 1024
#define EPSBN 1e-5f
#define NKB 21         // FIN/32

typedef _Float16 f16;
typedef __attribute__((ext_vector_type(8))) _Float16 half8;
typedef __attribute__((ext_vector_type(4))) float floatx4;

// S(h) for the 16-step LIF with constant drive h: spike period m = ceil(-log2(1-1/h)),
// S = sum over spikes q*m<=16 of KC[q*m-1]; exact dyadic values precomputed.
__device__ const float LIF_LUT[18] = {
    0.0f,
    0.93750095367431640625f,   // m=1  (0.9375 + 2^-20)
    0.4583339691162109375f,    // m=2
    0.294643402099609375f,     // m=3
    0.21666717529296875f,      // m=4
    0.1713714599609375f,       // m=5
    0.123016357421875f,        // m=6
    0.11712646484375f,         // m=7
    0.0936279296875f,          // m=8
    0.062255859375f,           // m=9
    0.06201171875f,            // m=10
    0.0615234375f,             // m=11
    0.060546875f,              // m=12
    0.05859375f,               // m=13
    0.0546875f,                // m=14
    0.046875f,                 // m=15
    0.03125f,                  // m=16
    0.0f                       // m>=17: no spike
};

// ---------------------------------------------------------------------------
// Fused prep: blocks [0,448) A planes (BN0 + f16 hi/lo, MFMA-A frag order);
// blocks [448,1120) W1 planes (f16 hi/lo, MFMA-B frag order).
// Frag layout: plane[(tile*NKB + kb)*64 + lane][8 f16]  (1 KB per frag chunk)
// ---------------------------------------------------------------------------
__global__ __launch_bounds__(256) void k_prep(
    const float* __restrict__ x, const float* __restrict__ w1,
    const float* __restrict__ g0, const float* __restrict__ b0,
    const float* __restrict__ m0, const float* __restrict__ v0,
    f16* __restrict__ Ah, f16* __restrict__ Al,
    f16* __restrict__ Wh, f16* __restrict__ Wl)
{
    __shared__ float sbuf[32 * 65];
    const int tid = threadIdx.x;
    const int b   = blockIdx.x;

    if (b < 448) {
        const int mb = b / 7;
        const int kc = b % 7;
        #pragma unroll
        for (int i = 0; i < 2; ++i) {
            const int f4 = tid + 256 * i;
            if (f4 < 384) {
                const int row = f4 / 24;
                const int c4  = (f4 % 24) * 4;
                float4 v = *(const float4*)(x + (size_t)(mb * 16 + row) * FIN + kc * 96 + c4);
                sbuf[row * 97 + c4 + 0] = v.x; sbuf[row * 97 + c4 + 1] = v.y;
                sbuf[row * 97 + c4 + 2] = v.z; sbuf[row * 97 + c4 + 3] = v.w;
            }
        }
        __syncthreads();
        if (tid < 192) {
            const int fi   = tid >> 6;          // 0..2 kb-in-chunk
            const int lane = tid & 63;
            const int row  = lane & 15;
            const int koff = fi * 32 + ((lane >> 4) << 3);
            const float a0  = g0[row] / sqrtf(v0[row] + EPSBN);
            const float be0 = b0[row] - m0[row] * a0;
            half8 hi, lo;
            #pragma unroll
            for (int j = 0; j < 8; ++j) {
                const float xn = fmaf(a0, sbuf[row * 97 + koff + j], be0);
                const f16 h = (f16)xn;
                hi[j] = h;
                lo[j] = (f16)(xn - (float)h);
            }
            const int kb = kc * 3 + fi;
            const size_t idx = ((size_t)(mb * NKB + kb) * 64 + lane);
            *(half8*)(Ah + idx * 8) = hi;
            *(half8*)(Al + idx * 8) = lo;
        }
    } else {
        const int bw = b - 448;
        const int ng = bw & 31;
        const int kb = bw >> 5;     // 0..20
        #pragma unroll
        for (int i = 0; i < 2; ++i) {
            const int f4  = tid + 256 * i;        // 0..511
            const int row = f4 >> 4;
            const int c4  = (f4 & 15) * 4;
            float4 v = *(const float4*)(w1 + (size_t)(kb * 32 + row) * HH + ng * 64 + c4);
            sbuf[row * 65 + c4 + 0] = v.x; sbuf[row * 65 + c4 + 1] = v.y;
            sbuf[row * 65 + c4 + 2] = v.z; sbuf[row * 65 + c4 + 3] = v.w;
        }
        __syncthreads();
        const int fi   = tid >> 6;     // 0..3
        const int lane = tid & 63;
        const int col  = fi * 16 + (lane & 15);
        const int kr   = (lane >> 4) << 3;
        half8 hi, lo;
        #pragma unroll
        for (int j = 0; j < 8; ++j) {
            const float wv = sbuf[(kr + j) * 65 + col];
            const f16 h = (f16)wv;
            hi[j] = h;
            lo[j] = (f16)(wv - (float)h);
        }
        const int nb = ng * 4 + fi;
        const size_t idx = ((size_t)(nb * NKB + kb) * 64 + lane);
        *(half8*)(Wh + idx * 8) = hi;
        *(half8*)(Wl + idx * 8) = lo;
    }
}

// ---------------------------------------------------------------------------
// GEMM1 via MFMA f16-split (hh+hl+lh), fused bias1/BN1/LIF -> S f16.
// 64-thr blocks (1 wave), wave tile 32x32 (2x2 frags), grid 2048
// -> 8 blocks/CU = 2 waves/SIMD.  __launch_bounds__(64,2) gives each wave
// up to 256 VGPR so the 3-deep register pipeline (3 x 8 half8 batches)
// survives regalloc; loads use {0,1024,2048} imm offsets + one ptr bump
// per 3 K-steps.  XCD swizzle: blockIdx&7 owns a 256-col W stripe -> per-XCD
// L2 set = A planes 2.75MB + stripe 0.69MB < 4MB.
// ---------------------------------------------------------------------------
__global__ __launch_bounds__(64, 2) void k_gemm1(
    const f16* __restrict__ Ah, const f16* __restrict__ Al,
    const f16* __restrict__ Wh, const f16* __restrict__ Wl,
    const float* __restrict__ bias1,
    const float* __restrict__ g1, const float* __restrict__ b1,
    const float* __restrict__ m1, const float* __restrict__ v1,
    f16* __restrict__ S)
{
    const int lane = threadIdx.x;
    const int b    = blockIdx.x;          // 0..2047
    const int xcd  = b & 7;
    const int bnl  = (b >> 3) & 7;
    const int bm   = b >> 6;              // 0..31 : 32-row tile
    const int bn   = xcd * 8 + bnl;       // 0..63 : 32-col tile
    const int mb0  = bm * 2;
    const int nb0  = bn * 2;

    const int lb = lane * 16;
    const char* pAh0 = (const char*)Ah + (size_t)(mb0 + 0) * NKB * 1024 + lb;
    const char* pAh1 = (const char*)Ah + (size_t)(mb0 + 1) * NKB * 1024 + lb;
    const char* pAl0 = (const char*)Al + (size_t)(mb0 + 0) * NKB * 1024 + lb;
    const char* pAl1 = (const char*)Al + (size_t)(mb0 + 1) * NKB * 1024 + lb;
    const char* pWh0 = (const char*)Wh + (size_t)(nb0 + 0) * NKB * 1024 + lb;
    const char* pWh1 = (const char*)Wh + (size_t)(nb0 + 1) * NKB * 1024 + lb;
    const char* pWl0 = (const char*)Wl + (size_t)(nb0 + 0) * NKB * 1024 + lb;
    const char* pWl1 = (const char*)Wl + (size_t)(nb0 + 1) * NKB * 1024 + lb;

    floatx4 acc00 = (floatx4){0.f,0.f,0.f,0.f};
    floatx4 acc01 = (floatx4){0.f,0.f,0.f,0.f};
    floatx4 acc10 = (floatx4){0.f,0.f,0.f,0.f};
    floatx4 acc11 = (floatx4){0.f,0.f,0.f,0.f};

    // three named batches (no runtime-indexed arrays -> stays in VGPRs)
    half8 A0h0,A0h1,A0l0,A0l1,W0h0,W0h1,W0l0,W0l1;
    half8 A1h0,A1h1,A1l0,A1l1,W1h0,W1h1,W1l0,W1l1;
    half8 A2h0,A2h1,A2l0,A2l1,W2h0,W2h1,W2l0,W2l1;

#define LOADB(P, off) do {                                                    \
    P##h0 = *(const half8*)(pAh0 + (off)); P##h1 = *(const half8*)(pAh1 + (off)); \
    P##l0 = *(const half8*)(pAl0 + (off)); P##l1 = *(const half8*)(pAl1 + (off)); \
    P##Wh0_ = *(const half8*)(pWh0 + (off)); P##Wh1_ = *(const half8*)(pWh1 + (off)); \
    P##Wl0_ = *(const half8*)(pWl0 + (off)); P##Wl1_ = *(const half8*)(pWl1 + (off)); \
} while (0)
#undef LOADB

#define LOADB(ah0,ah1,al0,al1,wh0,wh1,wl0,wl1, off) do {                      \
    ah0 = *(const half8*)(pAh0 + (off)); ah1 = *(const half8*)(pAh1 + (off)); \
    al0 = *(const half8*)(pAl0 + (off)); al1 = *(const half8*)(pAl1 + (off)); \
    wh0 = *(const half8*)(pWh0 + (off)); wh1 = *(const half8*)(pWh1 + (off)); \
    wl0 = *(const half8*)(pWl0 + (off)); wl1 = *(const half8*)(pWl1 + (off)); \
} while (0)

#define COMP(ah0,ah1,al0,al1,wh0,wh1,wl0,wl1) do {                            \
    acc00 = __builtin_amdgcn_mfma_f32_16x16x32_f16(ah0, wh0, acc00, 0,0,0);   \
    acc01 = __builtin_amdgcn_mfma_f32_16x16x32_f16(ah0, wh1, acc01, 0,0,0);   \
    acc10 = __builtin_amdgcn_mfma_f32_16x16x32_f16(ah1, wh0, acc10, 0,0,0);   \
    acc11 = __builtin_amdgcn_mfma_f32_16x16x32_f16(ah1, wh1, acc11, 0,0,0);   \
    acc00 = __builtin_amdgcn_mfma_f32_16x16x32_f16(ah0, wl0, acc00, 0,0,0);   \
    acc01 = __builtin_amdgcn_mfma_f32_16x16x32_f16(ah0, wl1, acc01, 0,0,0);   \
    acc10 = __builtin_amdgcn_mfma_f32_16x16x32_f16(ah1, wl0, acc10, 0,0,0);   \
    acc11 = __builtin_amdgcn_mfma_f32_16x16x32_f16(ah1, wl1, acc11, 0,0,0);   \
    acc00 = __builtin_amdgcn_mfma_f32_16x16x32_f16(al0, wh0, acc00, 0,0,0);   \
    acc01 = __builtin_amdgcn_mfma_f32_16x16x32_f16(al0, wh1, acc01, 0,0,0);   \
    acc10 = __builtin_amdgcn_mfma_f32_16x16x32_f16(al1, wh0, acc10, 0,0,0);   \
    acc11 = __builtin_amdgcn_mfma_f32_16x16x32_f16(al1, wh1, acc11, 0,0,0);   \
} while (0)

#define ADV() do { pAh0 += 3072; pAh1 += 3072; pAl0 += 3072; pAl1 += 3072;    \
                   pWh0 += 3072; pWh1 += 3072; pWl0 += 3072; pWl1 += 3072; } while (0)

    LOADB(A0h0,A0h1,A0l0,A0l1,W0h0,W0h1,W0l0,W0l1, 0);
    LOADB(A1h0,A1h1,A1l0,A1l1,W1h0,W1h1,W1l0,W1l1, 1024);

    #pragma unroll 1
    for (int t = 0; t < 6; ++t) {
        LOADB(A2h0,A2h1,A2l0,A2l1,W2h0,W2h1,W2l0,W2l1, 2048);
        COMP(A0h0,A0h1,A0l0,A0l1,W0h0,W0h1,W0l0,W0l1);
        ADV();
        LOADB(A0h0,A0h1,A0l0,A0l1,W0h0,W0h1,W0l0,W0l1, 0);
        COMP(A1h0,A1h1,A1l0,A1l1,W1h0,W1h1,W1l0,W1l1);
        LOADB(A1h0,A1h1,A1l0,A1l1,W1h0,W1h1,W1l0,W1l1, 1024);
        COMP(A2h0,A2h1,A2l0,A2l1,W2h0,W2h1,W2l0,W2l1);
    }
    // epilogue: kb 18,19,20
    LOADB(A2h0,A2h1,A2l0,A2l1,W2h0,W2h1,W2l0,W2l1, 2048);
    COMP(A0h0,A0h1,A0l0,A0l1,W0h0,W0h1,W0l0,W0l1);
    COMP(A1h0,A1h1,A1l0,A1l1,W1h0,W1h1,W1l0,W1l1);
    COMP(A2h0,A2h1,A2l0,A2l1,W2h0,W2h1,W2l0,W2l1);
#undef LOADB
#undef COMP
#undef ADV

    // ---- fused bias1 / BN1 / LIF-LUT epilogue -> S f16 ----
    const float H16 = (float)(65536.0 / 65535.0);
    const int   r4  = (lane >> 4) << 2;
    float a1c[4], be1c[4];
    #pragma unroll
    for (int j = 0; j < 4; ++j) {
        const int p = r4 + j;
        a1c[j]  = g1[p] / sqrtf(v1[p] + EPSBN);
        be1c[j] = b1[p] - m1[p] * a1c[j];
    }

    const floatx4* accs[4] = {&acc00, &acc01, &acc10, &acc11};
    #pragma unroll
    for (int m = 0; m < 2; ++m) {
        const int rowb = (mb0 + m) * 16 + r4;
        #pragma unroll
        for (int n = 0; n < 2; ++n) {
            const int col = (nb0 + n) * 16 + (lane & 15);
            const float bs = bias1[col];
            const floatx4 a4 = *accs[m * 2 + n];
            #pragma unroll
            for (int j = 0; j < 4; ++j) {
                const float h = fmaf(a1c[j], a4[j] + bs, be1c[j]);
                float s = 0.f;
                if (h >= H16) {
                    const float rr = 1.f - __builtin_amdgcn_rcpf(h);
                    int mi = (int)ceilf(-__log2f(rr));
                    mi = mi < 1 ? 1 : (mi > 17 ? 17 : mi);
                    s = LIF_LUT[mi];
                }
                S[(size_t)(rowb + j) * HH + col] = (f16)s;
            }
        }
    }
}

// ---------------------------------------------------------------------------
// GEMM2 partial (S f16, w2 staged in LDS) + finish (BN2/bias2/mean/tanh).
// ---------------------------------------------------------------------------
__global__ __launch_bounds__(256) void k_gemm2_part(
    const f16* __restrict__ S, const float* __restrict__ w2,
    float* __restrict__ part2)
{
    __shared__ float w2s[8192];
    const int tid = threadIdx.x;
    const int rg  = blockIdx.x;
    const int kc  = blockIdx.y;

    const float4* src = (const float4*)(w2 + (size_t)kc * 8192);
    #pragma unroll
    for (int i = tid; i < 2048; i += 256) ((float4*)w2s)[i] = src[i];
    __syncthreads();

    const int rw  = tid >> 5;
    const int col = tid & 31;
    const int row = rg * 8 + rw;
    const f16* Sp = S + (size_t)row * HH + kc * 256;

    float acc0 = 0.f, acc1 = 0.f;
    #pragma unroll 4
    for (int j = 0; j < 256; j += 8) {
        half8 s8 = *(const half8*)(Sp + j);
        acc0 = fmaf((float)s8[0], w2s[(j + 0) * 32 + col], acc0);
        acc1 = fmaf((float)s8[1], w2s[(j + 1) * 32 + col], acc1);
        acc0 = fmaf((float)s8[2], w2s[(j + 2) * 32 + col], acc0);
        acc1 = fmaf((float)s8[3], w2s[(j + 3) * 32 + col], acc1);
        acc0 = fmaf((float)s8[4], w2s[(j + 4) * 32 + col], acc0);
        acc1 = fmaf((float)s8[5], w2s[(j + 5) * 32 + col], acc1);
        acc0 = fmaf((float)s8[6], w2s[(j + 6) * 32 + col], acc0);
        acc1 = fmaf((float)s8[7], w2s[(j + 7) * 32 + col], acc1);
    }
    part2[((size_t)kc * MM + row) * AA + col] = acc0 + acc1;
}

__global__ __launch_bounds__(256) void k_finish(
    const float* __restrict__ part2, const float* __restrict__ bias2,
    const float* __restrict__ g2, const float* __restrict__ b2,
    const float* __restrict__ m2, const float* __restrict__ v2,
    float* __restrict__ out)
{
    const int i   = blockIdx.x * 256 + threadIdx.x;
    const int col = i & 31;
    const int row = i >> 5;
    const int p   = row & 15;
    float acc = 0.f;
    #pragma unroll
    for (int s = 0; s < 8; ++s) acc += part2[(size_t)s * MM * AA + i];
    const float a2   = g2[p] / sqrtf(v2[p] + EPSBN);
    const float be2  = b2[p] - m2[p] * a2;
    const float Csum = 0.9375f + 0x1p-20f;
    const float val  = fmaf(a2, acc + Csum * bias2[col], Csum * be2);
    out[i] = 2.0f * tanhf(val);
}

// ---------------------------------------------------------------------------
// Fallback fp32 GEMM1 (used only if ws too small) -> f16 S.
// ---------------------------------------------------------------------------
__global__ __launch_bounds__(256) void k_gemm1_fp32(
    const float* __restrict__ x, const float* __restrict__ w1,
    const float* __restrict__ bias1,
    const float* __restrict__ g0, const float* __restrict__ b0,
    const float* __restrict__ m0, const float* __restrict__ v0,
    const float* __restrict__ g1, const float* __restrict__ b1,
    const float* __restrict__ m1, const float* __restrict__ v1,
    f16* __restrict__ S)
{
    __shared__ float As[16][36];
    __shared__ float Bs[16][68];

    const int tid = threadIdx.x;
    const int bx  = blockIdx.x;
    const int by  = blockIdx.y;

    const int ar   = tid & 31;
    const int ak   = (tid >> 5) << 1;
    const int grow = by * 32 + ar;
    const int pA   = grow & 15;
    const float a0  = g0[pA] / sqrtf(v0[pA] + EPSBN);
    const float be0 = b0[pA] - m0[pA] * a0;
    const float* xrow = x + (size_t)grow * FIN;

    const int brk = tid >> 4;
    const int bcc = (tid & 15) << 2;
    const float* wp = w1 + (size_t)brk * HH + bx * 64 + bcc;

    const int tx = tid & 15;
    const int ty = tid >> 4;

    float acc[2][4];
    #pragma unroll
    for (int i = 0; i < 2; ++i)
        #pragma unroll
        for (int j = 0; j < 4; ++j) acc[i][j] = 0.f;

    float2 aPre = *(const float2*)(xrow + ak);
    float4 bPre = *(const float4*)(wp);

    for (int kt = 0; kt < FIN; kt += 16) {
        As[ak + 0][ar] = fmaf(a0, aPre.x, be0);
        As[ak + 1][ar] = fmaf(a0, aPre.y, be0);
        *(float4*)&Bs[brk][bcc] = bPre;
        __syncthreads();
        if (kt + 16 < FIN) {
            aPre = *(const float2*)(xrow + kt + 16 + ak);
            bPre = *(const float4*)(wp + (size_t)(kt + 16) * HH);
        }
        #pragma unroll
        for (int k = 0; k < 16; ++k) {
            float2 a2 = *(const float2*)&As[k][ty << 1];
            float4 b4 = *(const float4*)&Bs[k][tx << 2];
            float aa[2] = {a2.x, a2.y};
            float bb[4] = {b4.x, b4.y, b4.z, b4.w};
            #pragma unroll
            for (int i = 0; i < 2; ++i)
                #pragma unroll
                for (int j = 0; j < 4; ++j)
                    acc[i][j] = fmaf(aa[i], bb[j], acc[i][j]);
        }
        __syncthreads();
    }

    const float KC[16] = {
        (1.0f-0x1p-16f)*0.0625f,(1.0f-0x1p-15f)*0.0625f,(1.0f-0x1p-14f)*0.0625f,(1.0f-0x1p-13f)*0.0625f,
        (1.0f-0x1p-12f)*0.0625f,(1.0f-0x1p-11f)*0.0625f,(1.0f-0x1p-10f)*0.0625f,(1.0f-0x1p-9f)*0.0625f,
        (1.0f-0x1p-8f)*0.0625f,(1.0f-0x1p-7f)*0.0625f,(1.0f-0x1p-6f)*0.0625f,(1.0f-0x1p-5f)*0.0625f,
        (1.0f-0x1p-4f)*0.0625f,(1.0f-0x1p-3f)*0.0625f,(1.0f-0x1p-2f)*0.0625f,(1.0f-0x1p-1f)*0.0625f
    };

    const int col0 = bx * 64 + (tx << 2);
    float4 bias4 = *(const float4*)(bias1 + col0);
    const float bias_arr[4] = {bias4.x, bias4.y, bias4.z, bias4.w};

    #pragma unroll
    for (int i = 0; i < 2; ++i) {
        const int r = by * 32 + (ty << 1) + i;
        const int p = r & 15;
        const float a1  = g1[p] / sqrtf(v1[p] + EPSBN);
        const float be1 = b1[p] - m1[p] * a1;
        #pragma unroll
        for (int j = 0; j < 4; ++j) {
            const float h = fmaf(a1, acc[i][j] + bias_arr[j], be1);
            float v = 0.f, s = 0.f;
            #pragma unroll
            for (int t = 0; t < 16; ++t) {
                v = v + (h - v) * 0.5f;
                if (v >= 1.0f) { s += KC[t]; v = 0.f; }
            }
            S[(size_t)r * HH + col0 + j] = (f16)s;
        }
    }
}

extern "C" void kernel_launch(void* const* d_in, const int* in_sizes, int n_in,
                              void* d_out, int out_size, void* d_ws, size_t ws_size,
                              hipStream_t stream) {
    (void)in_sizes; (void)n_in; (void)out_size;
    const float* x     = (const float*)d_in[0];
    const float* w1    = (const float*)d_in[1];
    const float* bias1 = (const float*)d_in[2];
    const float* w2    = (const float*)d_in[3];
    const float* bias2 = (const float*)d_in[4];
    const float* g0 = (const float*)d_in[5];
    const float* b0 = (const float*)d_in[6];
    const float* m0 = (const float*)d_in[7];
    const float* v0 = (const float*)d_in[8];
    const float* g1 = (const float*)d_in[9];
    const float* b1 = (const float*)d_in[10];
    const float* m1 = (const float*)d_in[11];
    const float* v1 = (const float*)d_in[12];
    const float* g2 = (const float*)d_in[13];
    const float* b2 = (const float*)d_in[14];
    const float* m2 = (const float*)d_in[15];
    const float* v2 = (const float*)d_in[16];
    float* out = (float*)d_out;

    // ws: Ah 1.31M | Al 1.31M | Wh 2.62M | Wl 2.62M | S(f16) 4M | part2 1M
    const size_t offAl  = 1376256;
    const size_t offWh  = 2752512;
    const size_t offWl  = 5505024;
    const size_t offS   = 8257536;
    const size_t offP2  = offS + 4194304;
    const size_t needed = offP2 + 1048576;   // 13.5 MB

    if (ws_size >= needed) {
        f16* Ah = (f16*)d_ws;
        f16* Al = (f16*)((char*)d_ws + offAl);
        f16* Wh = (f16*)((char*)d_ws + offWh);
        f16* Wl = (f16*)((char*)d_ws + offWl);
        f16* S  = (f16*)((char*)d_ws + offS);
        float* part2 = (float*)((char*)d_ws + offP2);

        k_prep<<<1120, 256, 0, stream>>>(x, w1, g0, b0, m0, v0, Ah, Al, Wh, Wl);
        k_gemm1<<<2048, 64, 0, stream>>>(Ah, Al, Wh, Wl, bias1,
                                         g1, b1, m1, v1, S);
        k_gemm2_part<<<dim3(128, 8), 256, 0, stream>>>(S, w2, part2);
        k_finish<<<dim3(128), 256, 0, stream>>>(part2, bias2, g2, b2, m2, v2, out);
    } else {
        f16* S       = (f16*)d_ws;
        float* part2 = (float*)((char*)d_ws + (size_t)MM * HH * sizeof(f16));
        k_gemm1_fp32<<<dim3(32, 32), 256, 0, stream>>>(x, w1, bias1,
                                                       g0, b0, m0, v0,
                                                       g1, b1, m1, v1, S);
        k_gemm2_part<<<dim3(128, 8), 256, 0, stream>>>(S, w2, part2);
        k_finish<<<dim3(128), 256, 0, stream>>>(part2, bias2, g2, b2, m2, v2, out);
    }
}